// Round 11
// baseline (96.847 us; speedup 1.0000x reference)
//
#include <hip/hip_runtime.h>
#include <hip/hip_bf16.h>

// MHA forward: B=2, S=2048, D=HID=1024, H=16, hd=64. fp32 in/out, bf16 MFMA inside.

typedef __bf16 bf16;
typedef bf16 bf16x8 __attribute__((ext_vector_type(8)));
typedef float f32x4 __attribute__((ext_vector_type(4)));

#define MFMA16(Af, Bf, Cf) __builtin_amdgcn_mfma_f32_16x16x32_bf16((Af), (Bf), (Cf), 0, 0, 0)

__device__ __forceinline__ void gl_lds16(const void* g, void* l) {
    __builtin_amdgcn_global_load_lds(
        (const __attribute__((address_space(1))) void*)g,
        (__attribute__((address_space(3))) void*)l, 16, 0, 0);
}

__device__ __forceinline__ float exp2_fast(float x) {
    float r; asm("v_exp_f32 %0, %1" : "=v"(r) : "v"(x)); return r;
}

__device__ __forceinline__ bf16x8 cvt8(f32x4 a, f32x4 b) {
    bf16x8 o;
    o[0]=(bf16)a[0]; o[1]=(bf16)a[1]; o[2]=(bf16)a[2]; o[3]=(bf16)a[3];
    o[4]=(bf16)b[0]; o[5]=(bf16)b[1]; o[6]=(bf16)b[2]; o[7]=(bf16)b[3];
    return o;
}

// ---------------------------------------------------------------------------
// Kernel 0: fp32 -> bf16 pre-convert of Wq, Wk, Wv, Wo ONLY (x is now
// consumed as fp32 directly by qkv_gemm — saves 25 MB of HBM round-trip).
// 4 x 1M elems = 4M elems, 8/thread -> 2048 blocks.
// ---------------------------------------------------------------------------
__global__ __launch_bounds__(256) void cvt_all(
    const float* __restrict__ Wq, const float* __restrict__ Wk,
    const float* __restrict__ Wv, const float* __restrict__ Wo,
    bf16* __restrict__ wqb, bf16* __restrict__ wkb,
    bf16* __restrict__ wvb, bf16* __restrict__ wob)
{
    const size_t i8 = ((size_t)blockIdx.x * 256 + threadIdx.x) * 8;
    const float* src; bf16* dst; size_t off;
    if (i8 < 1048576)      { src = Wq; dst = wqb; off = i8; }
    else if (i8 < 2097152) { src = Wk; dst = wkb; off = i8 - 1048576; }
    else if (i8 < 3145728) { src = Wv; dst = wvb; off = i8 - 2097152; }
    else                   { src = Wo; dst = wob; off = i8 - 3145728; }
    f32x4 a = *reinterpret_cast<const f32x4*>(src + off);
    f32x4 b = *reinterpret_cast<const f32x4*>(src + off + 4);
    *reinterpret_cast<bf16x8*>(dst + off) = cvt8(a, b);
}

// ---------------------------------------------------------------------------
// Kernel 1: QKV projection. Round-3 core (512 threads / 8 waves, 128x128
// tile, wave=32x64, BK=64, dbuf 64 KB, 2 blocks/CU, 2-phase prefetch, one
// barrier/iter). NEW (this round): A consumed from fp32 x via reg-staging —
// issue f32x4 loads for tile t+1 BEFORE compute(t) (T14 split), convert and
// ds_write_b128 into the IDENTICAL swizzled LDS layout AFTER compute, then
// barrier. W keeps the global_load_lds path. Per-XCD x working set = 2.1 MB
// fp32 (4 tm panels) -> L2-resident next to the 2 MB W stream. All register
// indices static (rule #20). XCD swizzle: tm-chunk per XCD. Q pre-scaled by
// log2(e)/32. V written as V^T[bh][d][sigma(s)].
// ---------------------------------------------------------------------------
__global__ __launch_bounds__(512) void qkv_gemm(
    const float* __restrict__ xf,
    const bf16* __restrict__ wqb, const bf16* __restrict__ wkb,
    const bf16* __restrict__ wvb,
    const float* __restrict__ bq, const float* __restrict__ bk,
    const float* __restrict__ bv,
    bf16* __restrict__ qo, bf16* __restrict__ ko, bf16* __restrict__ vo)
{
    __shared__ __align__(16) char smem[65536];   // [As0 16K][Bs0 16K][As1 16K][Bs1 16K]

    const int which = blockIdx.y;
    const bf16* W     = (which == 0) ? wqb : (which == 1) ? wkb : wvb;
    const float* bia  = (which == 0) ? bq : (which == 1) ? bk : bv;
    bf16* outp        = (which == 0) ? qo : (which == 1) ? ko : vo;
    const float scale = (which == 0) ? 0.04508422f : 1.0f;   // log2(e)/32

    const int bid0 = blockIdx.x;
    const int xcd = bid0 & 7, j = bid0 >> 3;           // 256 = 8 XCD x 32
    const int tm = xcd * 4 + (j & 3);                  // XCD owns tm chunk of 4
    const int tn = j >> 2;                             // streams all 8 tn
    const int m0 = tm * 128, n0 = tn * 128;

    const int t = threadIdx.x;
    const int l = t & 63, w = t >> 6;                  // 8 waves
    const int wr = w >> 1, wc = w & 1;                 // wave = 32 rows x 64 cols
    const int lg = l >> 4, lr = l & 15;

    f32x4 acc[2][4];
#pragma unroll
    for (int i = 0; i < 2; ++i)
#pragma unroll
        for (int jj = 0; jj < 4; ++jj)
            acc[i][jj] = (f32x4){0.f, 0.f, 0.f, 0.f};

    // per-thread staging coordinates (2 chunks of 16 B each), hoisted
    const int c0 = w * 128 + l, c1 = c0 + 64;
    const int row0 = c0 >> 3, cc0 = (c0 & 7) ^ (row0 & 7);
    const int row1 = c1 >> 3, cc1 = (c1 & 7) ^ (row1 & 7);
    const float* aSrc0 = xf + (size_t)(m0 + row0) * 1024 + cc0 * 8;
    const float* aSrc1 = xf + (size_t)(m0 + row1) * 1024 + cc1 * 8;
    const bf16*  bSrc0 = W  + (size_t)(n0 + row0) * 1024 + cc0 * 8;
    const bf16*  bSrc1 = W  + (size_t)(n0 + row1) * 1024 + cc1 * 8;

    // stage W-tile (gl_lds) into buffer `base`
    auto stageB = [&](int kt, char* base) {
        gl_lds16(bSrc0 + kt, base + 16384 + c0 * 16);
        gl_lds16(bSrc1 + kt, base + 16384 + c1 * 16);
    };

    // prologue: stage tile 0 (A via regs, W via gl_lds); barrier drains both
    {
        f32x4 a0 = *reinterpret_cast<const f32x4*>(aSrc0);
        f32x4 a0h = *reinterpret_cast<const f32x4*>(aSrc0 + 4);
        f32x4 a1 = *reinterpret_cast<const f32x4*>(aSrc1);
        f32x4 a1h = *reinterpret_cast<const f32x4*>(aSrc1 + 4);
        stageB(0, smem);
        *reinterpret_cast<bf16x8*>(smem + c0 * 16) = cvt8(a0, a0h);
        *reinterpret_cast<bf16x8*>(smem + c1 * 16) = cvt8(a1, a1h);
    }
    __syncthreads();

    for (int it = 0; it < 16; ++it) {
        char* base = smem + ((it & 1) << 15);
        char* nextB = smem + (((it + 1) & 1) << 15);

        // issue next tile's loads BEFORE compute: W direct-to-LDS, A to regs
        f32x4 a0, a0h, a1, a1h;
        if (it < 15) {
            const int kt = (it + 1) * 64;
            stageB(kt, nextB);
            a0  = *reinterpret_cast<const f32x4*>(aSrc0 + kt);
            a0h = *reinterpret_cast<const f32x4*>(aSrc0 + kt + 4);
            a1  = *reinterpret_cast<const f32x4*>(aSrc1 + kt);
            a1h = *reinterpret_cast<const f32x4*>(aSrc1 + kt + 4);
        }

        char* AsB = base;
        char* BsB = base + 16384;

#pragma unroll
        for (int ks = 0; ks < 2; ++ks) {
            bf16x8 af[2], bff[4];
#pragma unroll
            for (int i = 0; i < 2; ++i) {
                const int ar = wr * 32 + i * 16 + lr;
                af[i]  = *reinterpret_cast<bf16x8*>(AsB + ar * 128 + ((ks * 64 + (lg << 4)) ^ ((ar & 7) << 4)));
            }
#pragma unroll
            for (int i = 0; i < 4; ++i) {
                const int br = wc * 64 + i * 16 + lr;
                bff[i] = *reinterpret_cast<bf16x8*>(BsB + br * 128 + ((ks * 64 + (lg << 4)) ^ ((br & 7) << 4)));
            }
            if (which == 2) {
#pragma unroll
                for (int mi = 0; mi < 2; ++mi)
#pragma unroll
                    for (int ni = 0; ni < 4; ++ni)
                        acc[mi][ni] = MFMA16(bff[ni], af[mi], acc[mi][ni]);  // C^T
            } else {
#pragma unroll
                for (int mi = 0; mi < 2; ++mi)
#pragma unroll
                    for (int ni = 0; ni < 4; ++ni)
                        acc[mi][ni] = MFMA16(af[mi], bff[ni], acc[mi][ni]);
            }
        }

        // write A(t+1) into the next buffer (loads had the compute phase
        // to land; compiler inserts the vmcnt wait before these ds_writes)
        if (it < 15) {
            *reinterpret_cast<bf16x8*>(nextB + c0 * 16) = cvt8(a0, a0h);
            *reinterpret_cast<bf16x8*>(nextB + c1 * 16) = cvt8(a1, a1h);
        }
        __syncthreads();
    }

    if (which == 2) {
        // D rows = hid col (wc*64+ni*16+lg*4+r), D cols = x row (wr*32+mi*16+lr)
#pragma unroll
        for (int ni = 0; ni < 4; ++ni) {
#pragma unroll
            for (int mi = 0; mi < 2; ++mi) {
#pragma unroll
                for (int r = 0; r < 4; ++r) {
                    const int col = n0 + wc * 64 + ni * 16 + lg * 4 + r;
                    const int h = col >> 6, d = col & 63;
                    const int rowg = m0 + wr * 32 + mi * 16 + lr;
                    const int b = rowg >> 11, s = rowg & 2047;
                    const int key = s & 127;
                    const int pos = (key & 96) | ((key & 12) << 1) | ((key & 16) >> 2) | (key & 3);
                    const float v = acc[mi][ni][r] + bia[col];
                    outp[((size_t)(b * 16 + h) * 64 + d) * 2048 + (s & ~127) + pos] = (bf16)v;
                }
            }
        }
    } else {
#pragma unroll
        for (int ni = 0; ni < 4; ++ni) {
            const int col = n0 + wc * 64 + ni * 16 + lr;
            const float bval = bia[col];
            const int h = col >> 6, d = col & 63;
#pragma unroll
            for (int mi = 0; mi < 2; ++mi) {
#pragma unroll
                for (int r = 0; r < 4; ++r) {
                    const int rowg = m0 + wr * 32 + mi * 16 + lg * 4 + r;
                    const int b = rowg >> 11, s = rowg & 2047;
                    const float v = (acc[mi][ni][r] + bval) * scale;
                    outp[((size_t)(b * 16 + h) * 2048 + s) * 64 + d] = (bf16)v;
                }
            }
        }
    }
}

// ---------------------------------------------------------------------------
// Kernel 2: flash attention, split-KV with KVBLK=64 (round-10 proven:
// 512 blocks x 8 waves; group 0 = KV tiles 0-15, group 1 = 16-31, same 128
// q-rows; dbuf K/V LDS 64 KB, 2-phase prefetch, ONE barrier per iteration;
// parallel combine tail with all-literal register indices). 39.8 us, 863 TF
// — converged at this structure per rounds 4-10.
// ---------------------------------------------------------------------------
__global__ __launch_bounds__(512, 4) void attn_kernel(
    const bf16* __restrict__ qb, const bf16* __restrict__ kb,
    const bf16* __restrict__ vb, bf16* __restrict__ ao)
{
    __shared__ __align__(16) char smem[65536];   // 2 x [g0 K][g1 K][g0 V][g1 V]

    const int bid0 = blockIdx.x;
    const int bid = ((bid0 & 7) << 6) | (bid0 >> 3);   // XCD chunked swizzle, 512%8==0
    const int qt = bid & 15, bh = bid >> 4;
    const int b = bh >> 4, h = bh & 15;
    const bf16* qp = qb + ((size_t)bh * 2048 + qt * 128) * 64;
    const bf16* kp = kb + (size_t)bh * 2048 * 64;
    const bf16* vt = vb + (size_t)bh * 64 * 2048;      // V^T [64][2048], cols permuted

    const int t = threadIdx.x;
    const int l = t & 63, w = t >> 6;          // 8 waves
    const int g = w >> 2, ws = w & 3;          // KV-group, wave-in-group
    const int lg = l >> 4, lr = l & 15;

    // Q fragments (MFMA B-operand): rows ws*32 + mt*16 + lr (same for both groups)
    bf16x8 qf[2][2];
#pragma unroll
    for (int mt = 0; mt < 2; ++mt)
#pragma unroll
        for (int ks = 0; ks < 2; ++ks)
            qf[mt][ks] = *reinterpret_cast<const bf16x8*>(
                qp + (ws * 32 + mt * 16 + lr) * 64 + ks * 32 + lg * 8);

    f32x4 oacc[2][4];
#pragma unroll
    for (int mt = 0; mt < 2; ++mt)
#pragma unroll
        for (int jj = 0; jj < 4; ++jj)
            oacc[mt][jj] = (f32x4){0.f, 0.f, 0.f, 0.f};
    f32x4 lacc[2];
    lacc[0] = (f32x4){0.f, 0.f, 0.f, 0.f};
    lacc[1] = (f32x4){0.f, 0.f, 0.f, 0.f};

    bf16x8 vone;
#pragma unroll
    for (int jj = 0; jj < 8; ++jj) vone[jj] = (bf16)1.0f;

    // stage K+V tile `it` of this group into buffer `base` (4 gl_lds16/thread)
    auto stageKV = [&](int it, char* base) {
        const int kt = g * 16 + it;                    // group's 64-key tile index
        const bf16* ksrc = kp + (size_t)kt * 4096;
        char* KsB = base + g * 8192;
        char* VtB = base + 16384 + g * 8192;
#pragma unroll
        for (int i = 0; i < 2; ++i) {
            const int c = ws * 128 + i * 64 + l;
            const int row = c >> 3, cc = (c & 7) ^ (row & 7);
            gl_lds16(ksrc + (size_t)row * 64 + cc * 8, KsB + c * 16);
        }
#pragma unroll
        for (int i = 0; i < 2; ++i) {
            const int c = ws * 128 + i * 64 + l;
            const int d = c >> 3, i16 = c & 7;
            gl_lds16(vt + (size_t)d * 2048 + kt * 64 + ((i16 ^ (d & 7)) << 3),
                     VtB + c * 16);
        }
    };

    // prologue: stage tile 0 into buffer 0 (syncthreads drains vmcnt)
    stageKV(0, smem);
    __syncthreads();

    for (int it = 0; it < 16; ++it) {
        char* base = smem + ((it & 1) << 15);
        // prefetch next tile into the other buffer BEFORE compute
        if (it < 15) stageKV(it + 1, smem + (((it + 1) & 1) << 15));

        char* KsB = base + g * 8192;               // this group's K tile [64 keys][64 d]
        char* VtB = base + 16384 + g * 8192;       // this group's V^T tile [64 d][64 pos]

        // QK^T swapped: sc[mt][nt] lane holds S^T[key = nt*16+lg*4+r][q = lr]
        f32x4 sc[2][4];
        __builtin_amdgcn_s_setprio(1);
#pragma unroll
        for (int nt = 0; nt < 4; ++nt) {
            sc[0][nt] = (f32x4){0.f, 0.f, 0.f, 0.f};
            sc[1][nt] = (f32x4){0.f, 0.f, 0.f, 0.f};
#pragma unroll
            for (int ks = 0; ks < 2; ++ks) {
                const int nrow = nt * 16 + lr;
                bf16x8 kf = *reinterpret_cast<bf16x8*>(
                    KsB + nrow * 128 + ((ks * 64 + (lg << 4)) ^ ((nrow & 7) << 4)));
                sc[0][nt] = MFMA16(kf, qf[0][ks], sc[0][nt]);   // kf reused x2
                sc[1][nt] = MFMA16(kf, qf[1][ks], sc[1][nt]);
            }
        }
        __builtin_amdgcn_s_setprio(0);

        // max-free softmax: p = exp2(s); pack P A-fragments
        bf16x8 pa[2][2];
#pragma unroll
        for (int mt = 0; mt < 2; ++mt)
#pragma unroll
            for (int k4 = 0; k4 < 2; ++k4)
#pragma unroll
                for (int jj = 0; jj < 8; ++jj)
                    pa[mt][k4][jj] = (bf16)exp2_fast(sc[mt][2 * k4 + (jj >> 2)][jj & 3]);

        // PV + ones-column row-sum; vf reused across both m-tiles
        __builtin_amdgcn_s_setprio(1);
#pragma unroll
        for (int k4 = 0; k4 < 2; ++k4) {
            lacc[0] = MFMA16(pa[0][k4], vone, lacc[0]);
            lacc[1] = MFMA16(pa[1][k4], vone, lacc[1]);
#pragma unroll
            for (int dt = 0; dt < 4; ++dt) {
                const int d = dt * 16 + lr;
                bf16x8 vf = *reinterpret_cast<bf16x8*>(
                    VtB + d * 128 + (((k4 << 6) + (lg << 4)) ^ ((d & 7) << 4)));
                oacc[0][dt] = MFMA16(pa[0][k4], vf, oacc[0][dt]);
                oacc[1][dt] = MFMA16(pa[1][k4], vf, oacc[1][dt]);
            }
        }
        __builtin_amdgcn_s_setprio(0);

        // single barrier per iteration: implicit vmcnt(0) waits the prefetch
        // (which had the whole compute phase to land) and releases the buffer
        // of tile it for overwrite in iteration it+1.
        __syncthreads();
    }

    // parallel combine + epilogue — ALL literal register indices (rule #20).
    // cb0 <- g1's mt=0 partials; cb1 <- g0's mt=1 partials (disjoint LDS).
    // Rows of 21 floats (21 coprime 32 -> 2 lanes/bank = free).
    {
        float* cb0 = (float*)smem;                     // region0: 21504 B
        float* cb1 = (float*)(smem + 24576);           // region1: 21504 B
        const int base = (ws * 64 + l) * 21;

        if (g == 1) {
#pragma unroll
            for (int dt = 0; dt < 4; ++dt)
#pragma unroll
                for (int r = 0; r < 4; ++r)
                    cb0[base + dt * 4 + r] = oacc[0][dt][r];
#pragma unroll
            for (int r = 0; r < 4; ++r)
                cb0[base + 16 + r] = lacc[0][r];
        } else {
#pragma unroll
            for (int dt = 0; dt < 4; ++dt)
#pragma unroll
                for (int r = 0; r < 4; ++r)
                    cb1[base + dt * 4 + r] = oacc[1][dt][r];
#pragma unroll
            for (int r = 0; r < 4; ++r)
                cb1[base + 16 + r] = lacc[1][r];
        }

        __syncthreads();

        if (g == 0) {
            float rl[4];
#pragma unroll
            for (int r = 0; r < 4; ++r)
                rl[r] = 1.0f / (lacc[0][r] + cb0[base + 16 + r]);
#pragma unroll
            for (int dt = 0; dt < 4; ++dt) {
#pragma unroll
                for (int r = 0; r < 4; ++r) {
                    const float v = oacc[0][dt][r] + cb0[base + dt * 4 + r];
                    const int qrow = qt * 128 + ws * 32 + lg * 4 + r;
                    const int col = h * 64 + dt * 16 + lr;
                    ao[((size_t)b * 2048 + qrow) * 1024 + col] = (bf16)(v * rl[r]);
                }
            }
        } else {
            float rl[4];
#pragma unroll
            for (int r = 0; r < 4; ++r)
                rl[r] = 1.0f / (lacc[1][r] + cb1[base + 16 + r]);
#pragma unroll
            for (int dt = 0; dt < 4; ++dt) {
#pragma unroll
                for (int r = 0; r < 4; ++r) {
                    const float v = oacc[1][dt][r] + cb1[base + dt * 4 + r];
                    const int qrow = qt * 128 + ws * 32 + 16 + lg * 4 + r;
                    const int col = h * 64 + dt * 16 + lr;
                    ao[((size_t)b * 2048 + qrow) * 1024 + col] = (bf16)(v * rl[r]);
                }
            }
        }
    }
}

// ---------------------------------------------------------------------------
// Kernel 3: output projection (round-3 proven). 512 threads / 8 waves,
// 128x64 tile, wave=32x32, 2-phase dbuf prefetch (48 KB LDS -> 3 blocks/CU).
// XCD swizzle. fp32 out.
// ---------------------------------------------------------------------------
__global__ __launch_bounds__(512) void out_gemm(
    const bf16* __restrict__ A, const bf16* __restrict__ Wb,
    const float* __restrict__ bo, float* __restrict__ out)
{
    __shared__ __align__(16) char smem[49152];   // 2 x ([As 16K][Bs 8K])

    const int bid0 = blockIdx.x;
    const int xcd = bid0 & 7, j = bid0 >> 3;           // 512 = 8 XCD x 64
    const int tm = xcd * 4 + (j & 3);                  // XCD owns tm chunk of 4
    const int tn = j >> 2;                             // 16 tn panels
    const int m0 = tm * 128, n0 = tn * 64;

    const int t = threadIdx.x;
    const int l = t & 63, w = t >> 6;                  // 8 waves
    const int wr = w >> 1, wc = w & 1;                 // wave = 32 rows x 32 cols
    const int lg = l >> 4, lr = l & 15;

    f32x4 acc[2][2];
#pragma unroll
    for (int i = 0; i < 2; ++i)
#pragma unroll
        for (int jj = 0; jj < 2; ++jj)
            acc[i][jj] = (f32x4){0.f, 0.f, 0.f, 0.f};

    auto stage = [&](int kt, char* base) {
        char* AsB = base;
        char* BsB = base + 16384;
#pragma unroll
        for (int i = 0; i < 2; ++i) {
            const int c = w * 128 + i * 64 + l;        // A: 1024 chunks
            const int row = c >> 3, cc = (c & 7) ^ (row & 7);
            gl_lds16(A + (size_t)(m0 + row) * 1024 + kt + cc * 8, AsB + c * 16);
        }
        {
            const int c = w * 64 + l;                  // B: 512 chunks, 1/thread
            const int row = c >> 3, cc = (c & 7) ^ (row & 7);
            gl_lds16(Wb + (size_t)(n0 + row) * 1024 + kt + cc * 8, BsB + c * 16);
        }
    };

    stage(0, smem);
    __syncthreads();

    for (int it = 0; it < 16; ++it) {
        char* base = smem + (it & 1) * 24576;
        if (it < 15) stage((it + 1) * 64, smem + ((it + 1) & 1) * 24576);
        char* AsB = base;
        char* BsB = base + 16384;

#pragma unroll
        for (int ks = 0; ks < 2; ++ks) {
            bf16x8 af[2], bff[2];
#pragma unroll
            for (int i = 0; i < 2; ++i) {
                const int ar = wr * 32 + i * 16 + lr;
                af[i] = *reinterpret_cast<bf16x8*>(AsB + ar * 128 + ((ks * 64 + (lg << 4)) ^ ((ar & 7) << 4)));
            }
#pragma unroll
            for (int i = 0; i < 2; ++i) {
                const int br = wc * 32 + i * 16 + lr;
                bff[i] = *reinterpret_cast<bf16x8*>(BsB + br * 128 + ((ks * 64 + (lg << 4)) ^ ((br & 7) << 4)));
            }
#pragma unroll
            for (int mi = 0; mi < 2; ++mi)
#pragma unroll
                for (int ni = 0; ni < 2; ++ni)
                    acc[mi][ni] = MFMA16(af[mi], bff[ni], acc[mi][ni]);
        }
        __syncthreads();
    }

#pragma unroll
    for (int ni = 0; ni < 2; ++ni) {
        const int col = n0 + wc * 32 + ni * 16 + lr;
        const float bval = bo[col];
#pragma unroll
        for (int mi = 0; mi < 2; ++mi) {
#pragma unroll
            for (int r = 0; r < 4; ++r) {
                const int rowg = m0 + wr * 32 + mi * 16 + lg * 4 + r;
                out[(size_t)rowg * 1024 + col] = acc[mi][ni][r] + bval;
            }
        }
    }
}

// ---------------------------------------------------------------------------
extern "C" void kernel_launch(void* const* d_in, const int* in_sizes, int n_in,
                              void* d_out, int out_size, void* d_ws, size_t ws_size,
                              hipStream_t stream) {
    (void)in_sizes; (void)n_in; (void)out_size; (void)ws_size;
    const float* x  = (const float*)d_in[0];
    const float* Wq = (const float*)d_in[1];
    const float* bq = (const float*)d_in[2];
    const float* Wk = (const float*)d_in[3];
    const float* bk = (const float*)d_in[4];
    const float* Wv = (const float*)d_in[5];
    const float* bv = (const float*)d_in[6];
    const float* Wo = (const float*)d_in[7];
    const float* bo = (const float*)d_in[8];
    float* out = (float*)d_out;

    bf16* xb   = (bf16*)d_ws;            // 4194304 (unused this round; layout kept)
    bf16* wqb  = xb   + 4194304;         // 1048576 each
    bf16* wkb  = wqb  + 1048576;
    bf16* wvb  = wkb  + 1048576;
    bf16* wob  = wvb  + 1048576;
    bf16* qbuf = wob  + 1048576;         // 4194304 each
    bf16* kbuf = qbuf + 4194304;
    bf16* vbuf = kbuf + 4194304;         // V^T [bh][64][2048], cols sigma-permuted
    bf16* aob  = vbuf + 4194304;

    cvt_all<<<2048, 256, 0, stream>>>(Wq, Wk, Wv, Wo, wqb, wkb, wvb, wob);
    qkv_gemm<<<dim3(256, 3), 512, 0, stream>>>(x, wqb, wkb, wvb, bq, bk, bv, qbuf, kbuf, vbuf);
    attn_kernel<<<512, 512, 0, stream>>>(qbuf, kbuf, vbuf, aob);
    out_gemm<<<512, 512, 0, stream>>>(aob, wob, bo, out);
}

// Round 12
// 88.515 us; speedup vs baseline: 1.0941x; 1.0941x over previous
//
#include <hip/hip_runtime.h>
#include <hip/hip_bf16.h>

// MHA forward: B=2, S=2048, D=HID=1024, H=16, hd=64. fp32 in/out, bf16 MFMA inside.
// ROUND 12: verbatim revert to the round-10 session best (88.66 us).
// Round-11's fp32-x fusion regressed qkv 29->51 us (reg-staging serial chain
// vs fire-and-forget global_load_lds); traffic saving < latency exposed.

typedef __bf16 bf16;
typedef bf16 bf16x8 __attribute__((ext_vector_type(8)));
typedef float f32x4 __attribute__((ext_vector_type(4)));

#define MFMA16(Af, Bf, Cf) __builtin_amdgcn_mfma_f32_16x16x32_bf16((Af), (Bf), (Cf), 0, 0, 0)

__device__ __forceinline__ void gl_lds16(const void* g, void* l) {
    __builtin_amdgcn_global_load_lds(
        (const __attribute__((address_space(1))) void*)g,
        (__attribute__((address_space(3))) void*)l, 16, 0, 0);
}

__device__ __forceinline__ float exp2_fast(float x) {
    float r; asm("v_exp_f32 %0, %1" : "=v"(r) : "v"(x)); return r;
}

// ---------------------------------------------------------------------------
// Kernel 0: fp32 -> bf16 pre-convert of x, Wq, Wk, Wv, Wo.
// ---------------------------------------------------------------------------
__global__ __launch_bounds__(256) void cvt_all(
    const float* __restrict__ x, const float* __restrict__ Wq,
    const float* __restrict__ Wk, const float* __restrict__ Wv,
    const float* __restrict__ Wo,
    bf16* __restrict__ xb, bf16* __restrict__ wqb, bf16* __restrict__ wkb,
    bf16* __restrict__ wvb, bf16* __restrict__ wob)
{
    const size_t i8 = ((size_t)blockIdx.x * 256 + threadIdx.x) * 8;
    const float* src; bf16* dst; size_t off;
    if (i8 < 4194304)      { src = x;  dst = xb;  off = i8; }
    else if (i8 < 5242880) { src = Wq; dst = wqb; off = i8 - 4194304; }
    else if (i8 < 6291456) { src = Wk; dst = wkb; off = i8 - 5242880; }
    else if (i8 < 7340032) { src = Wv; dst = wvb; off = i8 - 6291456; }
    else                   { src = Wo; dst = wob; off = i8 - 7340032; }
    f32x4 a = *reinterpret_cast<const f32x4*>(src + off);
    f32x4 b = *reinterpret_cast<const f32x4*>(src + off + 4);
    bf16x8 o;
    o[0]=(bf16)a[0]; o[1]=(bf16)a[1]; o[2]=(bf16)a[2]; o[3]=(bf16)a[3];
    o[4]=(bf16)b[0]; o[5]=(bf16)b[1]; o[6]=(bf16)b[2]; o[7]=(bf16)b[3];
    *reinterpret_cast<bf16x8*>(dst + off) = o;
}

// ---------------------------------------------------------------------------
// Kernel 1: QKV projection (round-3 proven). 512 threads / 8 waves, 128x128
// tile, wave=32x64, BK=64, 2-phase dbuf prefetch (64 KB LDS -> 2 blocks/CU).
// XCD swizzle: tm-chunk per XCD. Q pre-scaled by log2(e)/32. V written as
// V^T[bh][d][sigma(s)].
// ---------------------------------------------------------------------------
__global__ __launch_bounds__(512) void qkv_gemm(
    const bf16* __restrict__ xb,
    const bf16* __restrict__ wqb, const bf16* __restrict__ wkb,
    const bf16* __restrict__ wvb,
    const float* __restrict__ bq, const float* __restrict__ bk,
    const float* __restrict__ bv,
    bf16* __restrict__ qo, bf16* __restrict__ ko, bf16* __restrict__ vo)
{
    __shared__ __align__(16) char smem[65536];   // [As0 16K][Bs0 16K][As1 16K][Bs1 16K]

    const int which = blockIdx.y;
    const bf16* W     = (which == 0) ? wqb : (which == 1) ? wkb : wvb;
    const float* bia  = (which == 0) ? bq : (which == 1) ? bk : bv;
    bf16* outp        = (which == 0) ? qo : (which == 1) ? ko : vo;
    const float scale = (which == 0) ? 0.04508422f : 1.0f;   // log2(e)/32

    const int bid0 = blockIdx.x;
    const int xcd = bid0 & 7, j = bid0 >> 3;           // 256 = 8 XCD x 32
    const int tm = xcd * 4 + (j & 3);                  // XCD owns tm chunk of 4
    const int tn = j >> 2;                             // streams all 8 tn
    const int m0 = tm * 128, n0 = tn * 128;

    const int t = threadIdx.x;
    const int l = t & 63, w = t >> 6;                  // 8 waves
    const int wr = w >> 1, wc = w & 1;                 // wave = 32 rows x 64 cols
    const int lg = l >> 4, lr = l & 15;

    f32x4 acc[2][4];
#pragma unroll
    for (int i = 0; i < 2; ++i)
#pragma unroll
        for (int jj = 0; jj < 4; ++jj)
            acc[i][jj] = (f32x4){0.f, 0.f, 0.f, 0.f};

    // stage one 128x64 A-tile + B-tile at K offset kt into buffer `base`
    auto stage = [&](int kt, char* base) {
        char* AsB = base;
        char* BsB = base + 16384;
#pragma unroll
        for (int i = 0; i < 2; ++i) {
            const int c = w * 128 + i * 64 + l;        // 1024 chunks each
            const int row = c >> 3, cc = (c & 7) ^ (row & 7);
            gl_lds16(xb + (size_t)(m0 + row) * 1024 + kt + cc * 8, AsB + c * 16);
            gl_lds16(W  + (size_t)(n0 + row) * 1024 + kt + cc * 8, BsB + c * 16);
        }
    };

    stage(0, smem);
    __syncthreads();

    for (int it = 0; it < 16; ++it) {
        char* base = smem + ((it & 1) << 15);
        if (it < 15) stage((it + 1) * 64, smem + (((it + 1) & 1) << 15));
        char* AsB = base;
        char* BsB = base + 16384;

#pragma unroll
        for (int ks = 0; ks < 2; ++ks) {
            bf16x8 af[2], bff[4];
#pragma unroll
            for (int i = 0; i < 2; ++i) {
                const int ar = wr * 32 + i * 16 + lr;
                af[i]  = *reinterpret_cast<bf16x8*>(AsB + ar * 128 + ((ks * 64 + (lg << 4)) ^ ((ar & 7) << 4)));
            }
#pragma unroll
            for (int i = 0; i < 4; ++i) {
                const int br = wc * 64 + i * 16 + lr;
                bff[i] = *reinterpret_cast<bf16x8*>(BsB + br * 128 + ((ks * 64 + (lg << 4)) ^ ((br & 7) << 4)));
            }
            if (which == 2) {
#pragma unroll
                for (int mi = 0; mi < 2; ++mi)
#pragma unroll
                    for (int ni = 0; ni < 4; ++ni)
                        acc[mi][ni] = MFMA16(bff[ni], af[mi], acc[mi][ni]);  // C^T
            } else {
#pragma unroll
                for (int mi = 0; mi < 2; ++mi)
#pragma unroll
                    for (int ni = 0; ni < 4; ++ni)
                        acc[mi][ni] = MFMA16(af[mi], bff[ni], acc[mi][ni]);
            }
        }
        __syncthreads();
    }

    if (which == 2) {
        // D rows = hid col (wc*64+ni*16+lg*4+r), D cols = x row (wr*32+mi*16+lr)
#pragma unroll
        for (int ni = 0; ni < 4; ++ni) {
#pragma unroll
            for (int mi = 0; mi < 2; ++mi) {
#pragma unroll
                for (int r = 0; r < 4; ++r) {
                    const int col = n0 + wc * 64 + ni * 16 + lg * 4 + r;
                    const int h = col >> 6, d = col & 63;
                    const int rowg = m0 + wr * 32 + mi * 16 + lr;
                    const int b = rowg >> 11, s = rowg & 2047;
                    const int key = s & 127;
                    const int pos = (key & 96) | ((key & 12) << 1) | ((key & 16) >> 2) | (key & 3);
                    const float v = acc[mi][ni][r] + bia[col];
                    outp[((size_t)(b * 16 + h) * 64 + d) * 2048 + (s & ~127) + pos] = (bf16)v;
                }
            }
        }
    } else {
#pragma unroll
        for (int ni = 0; ni < 4; ++ni) {
            const int col = n0 + wc * 64 + ni * 16 + lr;
            const float bval = bia[col];
            const int h = col >> 6, d = col & 63;
#pragma unroll
            for (int mi = 0; mi < 2; ++mi) {
#pragma unroll
                for (int r = 0; r < 4; ++r) {
                    const int rowg = m0 + wr * 32 + mi * 16 + lg * 4 + r;
                    const int b = rowg >> 11, s = rowg & 2047;
                    const float v = (acc[mi][ni][r] + bval) * scale;
                    outp[((size_t)(b * 16 + h) * 2048 + s) * 64 + d] = (bf16)v;
                }
            }
        }
    }
}

// ---------------------------------------------------------------------------
// Kernel 2: flash attention, split-KV with KVBLK=64 (round-10 proven:
// 512 blocks x 8 waves; group 0 = KV tiles 0-15, group 1 = 16-31, same 128
// q-rows; dbuf K/V LDS 64 KB, 2-phase prefetch, ONE barrier per iteration;
// parallel combine tail with all-literal register indices — rule #20).
// ---------------------------------------------------------------------------
__global__ __launch_bounds__(512, 4) void attn_kernel(
    const bf16* __restrict__ qb, const bf16* __restrict__ kb,
    const bf16* __restrict__ vb, bf16* __restrict__ ao)
{
    __shared__ __align__(16) char smem[65536];   // 2 x [g0 K][g1 K][g0 V][g1 V]

    const int bid0 = blockIdx.x;
    const int bid = ((bid0 & 7) << 6) | (bid0 >> 3);   // XCD chunked swizzle, 512%8==0
    const int qt = bid & 15, bh = bid >> 4;
    const int b = bh >> 4, h = bh & 15;
    const bf16* qp = qb + ((size_t)bh * 2048 + qt * 128) * 64;
    const bf16* kp = kb + (size_t)bh * 2048 * 64;
    const bf16* vt = vb + (size_t)bh * 64 * 2048;      // V^T [64][2048], cols permuted

    const int t = threadIdx.x;
    const int l = t & 63, w = t >> 6;          // 8 waves
    const int g = w >> 2, ws = w & 3;          // KV-group, wave-in-group
    const int lg = l >> 4, lr = l & 15;

    // Q fragments (MFMA B-operand): rows ws*32 + mt*16 + lr (same for both groups)
    bf16x8 qf[2][2];
#pragma unroll
    for (int mt = 0; mt < 2; ++mt)
#pragma unroll
        for (int ks = 0; ks < 2; ++ks)
            qf[mt][ks] = *reinterpret_cast<const bf16x8*>(
                qp + (ws * 32 + mt * 16 + lr) * 64 + ks * 32 + lg * 8);

    f32x4 oacc[2][4];
#pragma unroll
    for (int mt = 0; mt < 2; ++mt)
#pragma unroll
        for (int jj = 0; jj < 4; ++jj)
            oacc[mt][jj] = (f32x4){0.f, 0.f, 0.f, 0.f};
    f32x4 lacc[2];
    lacc[0] = (f32x4){0.f, 0.f, 0.f, 0.f};
    lacc[1] = (f32x4){0.f, 0.f, 0.f, 0.f};

    bf16x8 vone;
#pragma unroll
    for (int jj = 0; jj < 8; ++jj) vone[jj] = (bf16)1.0f;

    // stage K+V tile `it` of this group into buffer `base` (4 gl_lds16/thread)
    auto stageKV = [&](int it, char* base) {
        const int kt = g * 16 + it;                    // group's 64-key tile index
        const bf16* ksrc = kp + (size_t)kt * 4096;
        char* KsB = base + g * 8192;
        char* VtB = base + 16384 + g * 8192;
#pragma unroll
        for (int i = 0; i < 2; ++i) {
            const int c = ws * 128 + i * 64 + l;
            const int row = c >> 3, cc = (c & 7) ^ (row & 7);
            gl_lds16(ksrc + (size_t)row * 64 + cc * 8, KsB + c * 16);
        }
#pragma unroll
        for (int i = 0; i < 2; ++i) {
            const int c = ws * 128 + i * 64 + l;
            const int d = c >> 3, i16 = c & 7;
            gl_lds16(vt + (size_t)d * 2048 + kt * 64 + ((i16 ^ (d & 7)) << 3),
                     VtB + c * 16);
        }
    };

    // prologue: stage tile 0 into buffer 0 (syncthreads drains vmcnt)
    stageKV(0, smem);
    __syncthreads();

    for (int it = 0; it < 16; ++it) {
        char* base = smem + ((it & 1) << 15);
        // prefetch next tile into the other buffer BEFORE compute
        if (it < 15) stageKV(it + 1, smem + (((it + 1) & 1) << 15));

        char* KsB = base + g * 8192;               // this group's K tile [64 keys][64 d]
        char* VtB = base + 16384 + g * 8192;       // this group's V^T tile [64 d][64 pos]

        // QK^T swapped: sc[mt][nt] lane holds S^T[key = nt*16+lg*4+r][q = lr]
        f32x4 sc[2][4];
        __builtin_amdgcn_s_setprio(1);
#pragma unroll
        for (int nt = 0; nt < 4; ++nt) {
            sc[0][nt] = (f32x4){0.f, 0.f, 0.f, 0.f};
            sc[1][nt] = (f32x4){0.f, 0.f, 0.f, 0.f};
#pragma unroll
            for (int ks = 0; ks < 2; ++ks) {
                const int nrow = nt * 16 + lr;
                bf16x8 kf = *reinterpret_cast<bf16x8*>(
                    KsB + nrow * 128 + ((ks * 64 + (lg << 4)) ^ ((nrow & 7) << 4)));
                sc[0][nt] = MFMA16(kf, qf[0][ks], sc[0][nt]);   // kf reused x2
                sc[1][nt] = MFMA16(kf, qf[1][ks], sc[1][nt]);
            }
        }
        __builtin_amdgcn_s_setprio(0);

        // max-free softmax: p = exp2(s); pack P A-fragments
        bf16x8 pa[2][2];
#pragma unroll
        for (int mt = 0; mt < 2; ++mt)
#pragma unroll
            for (int k4 = 0; k4 < 2; ++k4)
#pragma unroll
                for (int jj = 0; jj < 8; ++jj)
                    pa[mt][k4][jj] = (bf16)exp2_fast(sc[mt][2 * k4 + (jj >> 2)][jj & 3]);

        // PV + ones-column row-sum; vf reused across both m-tiles
        __builtin_amdgcn_s_setprio(1);
#pragma unroll
        for (int k4 = 0; k4 < 2; ++k4) {
            lacc[0] = MFMA16(pa[0][k4], vone, lacc[0]);
            lacc[1] = MFMA16(pa[1][k4], vone, lacc[1]);
#pragma unroll
            for (int dt = 0; dt < 4; ++dt) {
                const int d = dt * 16 + lr;
                bf16x8 vf = *reinterpret_cast<bf16x8*>(
                    VtB + d * 128 + (((k4 << 6) + (lg << 4)) ^ ((d & 7) << 4)));
                oacc[0][dt] = MFMA16(pa[0][k4], vf, oacc[0][dt]);
                oacc[1][dt] = MFMA16(pa[1][k4], vf, oacc[1][dt]);
            }
        }
        __builtin_amdgcn_s_setprio(0);

        // single barrier per iteration: implicit vmcnt(0) waits the prefetch
        // (which had the whole compute phase to land) and releases the buffer
        // of tile it for overwrite in iteration it+1.
        __syncthreads();
    }

    // parallel combine + epilogue — ALL literal register indices (rule #20).
    // cb0 <- g1's mt=0 partials; cb1 <- g0's mt=1 partials (disjoint LDS).
    // Rows of 21 floats (21 coprime 32 -> 2 lanes/bank = free).
    {
        float* cb0 = (float*)smem;                     // region0: 21504 B
        float* cb1 = (float*)(smem + 24576);           // region1: 21504 B
        const int base = (ws * 64 + l) * 21;

        if (g == 1) {
#pragma unroll
            for (int dt = 0; dt < 4; ++dt)
#pragma unroll
                for (int r = 0; r < 4; ++r)
                    cb0[base + dt * 4 + r] = oacc[0][dt][r];
#pragma unroll
            for (int r = 0; r < 4; ++r)
                cb0[base + 16 + r] = lacc[0][r];
        } else {
#pragma unroll
            for (int dt = 0; dt < 4; ++dt)
#pragma unroll
                for (int r = 0; r < 4; ++r)
                    cb1[base + dt * 4 + r] = oacc[1][dt][r];
#pragma unroll
            for (int r = 0; r < 4; ++r)
                cb1[base + 16 + r] = lacc[1][r];
        }

        __syncthreads();

        if (g == 0) {
            float rl[4];
#pragma unroll
            for (int r = 0; r < 4; ++r)
                rl[r] = 1.0f / (lacc[0][r] + cb0[base + 16 + r]);
#pragma unroll
            for (int dt = 0; dt < 4; ++dt) {
#pragma unroll
                for (int r = 0; r < 4; ++r) {
                    const float v = oacc[0][dt][r] + cb0[base + dt * 4 + r];
                    const int qrow = qt * 128 + ws * 32 + lg * 4 + r;
                    const int col = h * 64 + dt * 16 + lr;
                    ao[((size_t)b * 2048 + qrow) * 1024 + col] = (bf16)(v * rl[r]);
                }
            }
        } else {
            float rl[4];
#pragma unroll
            for (int r = 0; r < 4; ++r)
                rl[r] = 1.0f / (lacc[1][r] + cb1[base + 16 + r]);
#pragma unroll
            for (int dt = 0; dt < 4; ++dt) {
#pragma unroll
                for (int r = 0; r < 4; ++r) {
                    const float v = oacc[1][dt][r] + cb1[base + dt * 4 + r];
                    const int qrow = qt * 128 + ws * 32 + 16 + lg * 4 + r;
                    const int col = h * 64 + dt * 16 + lr;
                    ao[((size_t)b * 2048 + qrow) * 1024 + col] = (bf16)(v * rl[r]);
                }
            }
        }
    }
}

// ---------------------------------------------------------------------------
// Kernel 3: output projection (round-3 proven). 512 threads / 8 waves,
// 128x64 tile, wave=32x32, 2-phase dbuf prefetch (48 KB LDS -> 3 blocks/CU).
// XCD swizzle. fp32 out.
// ---------------------------------------------------------------------------
__global__ __launch_bounds__(512) void out_gemm(
    const bf16* __restrict__ A, const bf16* __restrict__ Wb,
    const float* __restrict__ bo, float* __restrict__ out)
{
    __shared__ __align__(16) char smem[49152];   // 2 x ([As 16K][Bs 8K])

    const int bid0 = blockIdx.x;
    const int xcd = bid0 & 7, j = bid0 >> 3;           // 512 = 8 XCD x 64
    const int tm = xcd * 4 + (j & 3);                  // XCD owns tm chunk of 4
    const int tn = j >> 2;                             // 16 tn panels
    const int m0 = tm * 128, n0 = tn * 64;

    const int t = threadIdx.x;
    const int l = t & 63, w = t >> 6;                  // 8 waves
    const int wr = w >> 1, wc = w & 1;                 // wave = 32 rows x 32 cols
    const int lg = l >> 4, lr = l & 15;

    f32x4 acc[2][2];
#pragma unroll
    for (int i = 0; i < 2; ++i)
#pragma unroll
        for (int jj = 0; jj < 2; ++jj)
            acc[i][jj] = (f32x4){0.f, 0.f, 0.f, 0.f};

    auto stage = [&](int kt, char* base) {
        char* AsB = base;
        char* BsB = base + 16384;
#pragma unroll
        for (int i = 0; i < 2; ++i) {
            const int c = w * 128 + i * 64 + l;        // A: 1024 chunks
            const int row = c >> 3, cc = (c & 7) ^ (row & 7);
            gl_lds16(A + (size_t)(m0 + row) * 1024 + kt + cc * 8, AsB + c * 16);
        }
        {
            const int c = w * 64 + l;                  // B: 512 chunks, 1/thread
            const int row = c >> 3, cc = (c & 7) ^ (row & 7);
            gl_lds16(Wb + (size_t)(n0 + row) * 1024 + kt + cc * 8, BsB + c * 16);
        }
    };

    stage(0, smem);
    __syncthreads();

    for (int it = 0; it < 16; ++it) {
        char* base = smem + (it & 1) * 24576;
        if (it < 15) stage((it + 1) * 64, smem + ((it + 1) & 1) * 24576);
        char* AsB = base;
        char* BsB = base + 16384;

#pragma unroll
        for (int ks = 0; ks < 2; ++ks) {
            bf16x8 af[2], bff[2];
#pragma unroll
            for (int i = 0; i < 2; ++i) {
                const int ar = wr * 32 + i * 16 + lr;
                af[i] = *reinterpret_cast<bf16x8*>(AsB + ar * 128 + ((ks * 64 + (lg << 4)) ^ ((ar & 7) << 4)));
            }
#pragma unroll
            for (int i = 0; i < 2; ++i) {
                const int br = wc * 32 + i * 16 + lr;
                bff[i] = *reinterpret_cast<bf16x8*>(BsB + br * 128 + ((ks * 64 + (lg << 4)) ^ ((br & 7) << 4)));
            }
#pragma unroll
            for (int mi = 0; mi < 2; ++mi)
#pragma unroll
                for (int ni = 0; ni < 2; ++ni)
                    acc[mi][ni] = MFMA16(af[mi], bff[ni], acc[mi][ni]);
        }
        __syncthreads();
    }

#pragma unroll
    for (int ni = 0; ni < 2; ++ni) {
        const int col = n0 + wc * 32 + ni * 16 + lr;
        const float bval = bo[col];
#pragma unroll
        for (int mi = 0; mi < 2; ++mi) {
#pragma unroll
            for (int r = 0; r < 4; ++r) {
                const int rowg = m0 + wr * 32 + mi * 16 + lg * 4 + r;
                out[(size_t)rowg * 1024 + col] = acc[mi][ni][r] + bval;
            }
        }
    }
}

// ---------------------------------------------------------------------------
extern "C" void kernel_launch(void* const* d_in, const int* in_sizes, int n_in,
                              void* d_out, int out_size, void* d_ws, size_t ws_size,
                              hipStream_t stream) {
    (void)in_sizes; (void)n_in; (void)out_size; (void)ws_size;
    const float* x  = (const float*)d_in[0];
    const float* Wq = (const float*)d_in[1];
    const float* bq = (const float*)d_in[2];
    const float* Wk = (const float*)d_in[3];
    const float* bk = (const float*)d_in[4];
    const float* Wv = (const float*)d_in[5];
    const float* bv = (const float*)d_in[6];
    const float* Wo = (const float*)d_in[7];
    const float* bo = (const float*)d_in[8];
    float* out = (float*)d_out;

    bf16* xb   = (bf16*)d_ws;            // 4194304
    bf16* wqb  = xb   + 4194304;         // 1048576 each
    bf16* wkb  = wqb  + 1048576;
    bf16* wvb  = wkb  + 1048576;
    bf16* wob  = wvb  + 1048576;
    bf16* qbuf = wob  + 1048576;         // 4194304 each
    bf16* kbuf = qbuf + 4194304;
    bf16* vbuf = kbuf + 4194304;         // V^T [bh][64][2048], cols sigma-permuted
    bf16* aob  = vbuf + 4194304;

    cvt_all<<<4096, 256, 0, stream>>>(x, Wq, Wk, Wv, Wo, xb, wqb, wkb, wvb, wob);
    qkv_gemm<<<dim3(256, 3), 512, 0, stream>>>(xb, wqb, wkb, wvb, bq, bk, bv, qbuf, kbuf, vbuf);
    attn_kernel<<<512, 512, 0, stream>>>(qbuf, kbuf, vbuf, aob);
    out_gemm<<<512, 512, 0, stream>>>(aob, wob, bo, out);
}